// Round 10
// baseline (189.314 us; speedup 1.0000x reference)
//
#include <hip/hip_runtime.h>
#include <math.h>

#define N 256
#define G 2
#define BLK 512
#define S1 12         // Krylov steps, sweep 1
#define S2 10         // Krylov steps, sweep 2
#define SP1 13        // S1+1
#define VS 268        // f32 K row stride (words), 16B-aligned
#define UTS 280       // f16 uT row stride
#define RIDGE 3e-5f

typedef _Float16 half8v __attribute__((ext_vector_type(8)));
typedef float float4v __attribute__((ext_vector_type(4)));

// ---- LDS arena (bytes), 16-aligned ----
#define OFF_K     0          // SP1*G*VS*4 = 27872 : K[(i*G+g)*VS + c]
#define OFF_UT    27872      // 16*UTS*2 = 8960 (rows 2..15 garbage-read by B-frags)
#define OFF_ZTW   36832      // 8 waves * 2 rowblocks * G * 16 * 4 = 4096
#define OFF_PART  40928      // 16*4 = 64
#define OFF_NU    40992      // SP1*G*4 = 104 -> pad 112
#define OFF_INV   41104      // 112
#define OFF_GRAM  41216      // SP1*SP1*G*4 = 1352 -> 1360
#define OFF_L     42576      // S1*S1*G*4 = 1152
#define OFF_D     43728      // S1*G*4 = 96
#define ARENA_SZ  43824

// per-wave partial reduce for G=2 (lanes tid = c*2 + g)
__device__ __forceinline__ void red_write(float p, float* part, int lane, int wv) {
    p += __shfl_down(p, 2);
    p += __shfl_down(p, 4);
    p += __shfl_down(p, 8);
    p += __shfl_down(p, 16);
    p += __shfl_down(p, 32);
    if (lane < 2) part[wv * 2 + lane] = p;   // lane == g
}

// B-fragment read: lane provides B[k=32t+8mq+j][n=mn].
#define LD_FRAG(base, t) (*(const half8v*)((base) + mn * UTS + 32 * (t) + 8 * mq))

// zm = (S (x.*q))[c] for this thread's (c,g); q staged f16 in uT.
// Wave wv owns S rows [32wv, 32wv+32) as two 16-row MFMA blocks.
#define MATVEC(dst) do {                                                               \
    float4v acc0 = {0.f, 0.f, 0.f, 0.f};                                               \
    float4v acc1 = {0.f, 0.f, 0.f, 0.f};                                               \
    _Pragma("unroll")                                                                  \
    for (int t = 0; t < 8; ++t) {                                                      \
        half8v bf = LD_FRAG(uT, t);                                                    \
        acc0 = __builtin_amdgcn_mfma_f32_16x16x32_f16(Shi0[t], bf, acc0, 0, 0, 0);     \
        acc1 = __builtin_amdgcn_mfma_f32_16x16x32_f16(Shi1[t], bf, acc1, 0, 0, 0);     \
    }                                                                                  \
    if (mn < 2) {                                                                      \
        *(float4v*)(zTw + ((wv * 2 + 0) * 2 + mn) * 16 + mq * 4) = acc0;               \
        *(float4v*)(zTw + ((wv * 2 + 1) * 2 + mn) * 16 + mq * 4) = acc1;               \
    }                                                                                  \
    dst = zTw[((wv * 2 + ((c >> 4) & 1)) * 2 + g) * 16 + (c & 15)];   /* intra-wave */ \
} while (0)

// CA-GMRES + fp32 IR, 2 systems per 512-thread block (2 blocks/CU for overlap).
__global__ __launch_bounds__(BLK, 4) void cayley_v10(const float* __restrict__ x_all,
                                                     const float* __restrict__ P,
                                                     const float* __restrict__ v_in,
                                                     float* __restrict__ out, int batch) {
    __shared__ __align__(16) char arena[ARENA_SZ];
    float* sK      = (float*)(arena + OFF_K);
    _Float16* uT   = (_Float16*)(arena + OFF_UT);
    float* zTw     = (float*)(arena + OFF_ZTW);
    float* sPart   = (float*)(arena + OFF_PART);
    float* sNu     = (float*)(arena + OFF_NU);
    float* sInv    = (float*)(arena + OFF_INV);
    float* sGram   = (float*)(arena + OFF_GRAM);
    float* sL      = (float*)(arena + OFF_L);
    float* sD      = (float*)(arena + OFF_D);

    const int tid = threadIdx.x;
    const int lane = tid & 63, wv = tid >> 6;        // 8 waves
    const int mn = lane & 15, mq = lane >> 4;        // MFMA fragment coords
    const int c = tid >> 1, g = tid & 1;             // solver coords (c: 0..255)
    const int sys = blockIdx.x * G + g;
    const bool alive = sys < batch;

    // ---- preamble: S = P - P^T rows [32wv,32wv+32) as f16 A-fragments ----
    half8v Shi0[8], Shi1[8];
#pragma unroll
    for (int rb = 0; rb < 2; ++rb) {
        const int r = 32 * wv + 16 * rb + mn;
#pragma unroll
        for (int t = 0; t < 8; ++t) {
            const int k0 = 32 * t + 8 * mq;
            float4v pa = *(const float4v*)(P + r * N + k0);
            float4v pb = *(const float4v*)(P + r * N + k0 + 4);
            half8v hi;
            hi[0] = (_Float16)(pa.x - P[(k0 + 0) * N + r]);
            hi[1] = (_Float16)(pa.y - P[(k0 + 1) * N + r]);
            hi[2] = (_Float16)(pa.z - P[(k0 + 2) * N + r]);
            hi[3] = (_Float16)(pa.w - P[(k0 + 3) * N + r]);
            hi[4] = (_Float16)(pb.x - P[(k0 + 4) * N + r]);
            hi[5] = (_Float16)(pb.y - P[(k0 + 5) * N + r]);
            hi[6] = (_Float16)(pb.z - P[(k0 + 6) * N + r]);
            hi[7] = (_Float16)(pb.w - P[(k0 + 7) * N + r]);
            if (rb == 0) Shi0[t] = hi; else Shi1[t] = hi;
        }
    }

    const float x_own = alive ? x_all[sys * N + c] : 0.f;
    const float v_own = v_in[c];
    float wsol = 0.f;

    for (int sw = 0; sw < 2; ++sw) {
        const int s = sw ? S2 : S1;

        // ---- K_0 candidate: fp32 residual through the f16 operator ----
        float z;
        if (sw == 0) {
            z = alive ? v_own : 0.f;
        } else {
            uT[g * UTS + c] = (_Float16)(x_own * wsol);
            __syncthreads();
            float zm;
            MATVEC(zm);
            z = alive ? (v_own - wsol - zm) : 0.f;
        }

        // ---- basis build: normalize, store, matvec; 2 barriers/step ----
        for (int i = 0;; ++i) {
            red_write(z * z, sPart, lane, wv);
            __syncthreads();                               // partials ready
            float pv = sPart[lane & 15];                   // slots: wv'*2+g'
            pv += __shfl_xor(pv, 2);
            pv += __shfl_xor(pv, 4);
            pv += __shfl_xor(pv, 8);                       // class-sum for g = lane&1
            const float inv = (pv > 1e-30f) ? (1.f / sqrtf(pv)) : 0.f;
            const float kq = z * inv;
            sK[(i * G + g) * VS + c] = kq;
            if (tid < 2) {                                 // tid == g
                sNu[i * G + tid] = pv * inv;               // nu_i
                sInv[i * G + tid] = inv;
            }
            if (i == s) break;
            uT[g * UTS + c] = (_Float16)(x_own * kq);
            __syncthreads();                               // uT (and sK) visible
            float zm;
            MATVEC(zm);
            z = kq + zm;                                   // A khat_i
        }
        __syncthreads();   // K_s, sNu, sInv visible

        // ---- Gram pass: all pairs i<j over 8 waves ----
        const int NP = s * (s + 1) / 2;
        for (int pp = wv; pp < NP; pp += 8) {
            int i = 0, rem = pp;
            while (rem >= s - i) { rem -= (s - i); ++i; }
            const int j = i + 1 + rem;
            const int gq = lane >> 5, q = lane & 31;       // 32 lanes per system
            const float* ka = sK + (i * G + gq) * VS + 8 * q;
            const float* kb = sK + (j * G + gq) * VS + 8 * q;
            float p;
            {
                float4v a0 = *(const float4v*)(ka);
                float4v b0 = *(const float4v*)(kb);
                float4v a1 = *(const float4v*)(ka + 4);
                float4v b1 = *(const float4v*)(kb + 4);
                p = a0.x * b0.x;
                p = fmaf(a0.y, b0.y, p); p = fmaf(a0.z, b0.z, p); p = fmaf(a0.w, b0.w, p);
                p = fmaf(a1.x, b1.x, p); p = fmaf(a1.y, b1.y, p);
                p = fmaf(a1.z, b1.z, p); p = fmaf(a1.w, b1.w, p);
            }
            p += __shfl_xor(p, 1); p += __shfl_xor(p, 2);
            p += __shfl_xor(p, 4); p += __shfl_xor(p, 8);
            p += __shfl_xor(p, 16);
            if (q == 0) {
                sGram[(i * SP1 + j) * G + gq] = p;
                sGram[(j * SP1 + i) * G + gq] = p;
            }
        }
        __syncthreads();

        // ---- per-system LSQ: (Gram[1:,1:] + ridge) chat = Gram[1:,0],
        // wave-parallel Cholesky (wv<2 -> system wv; lanes = rows) ----
        if (wv < 2) {
            const int gq = wv;
            const int rr = lane;
            for (int k = 0; k < s; ++k) {
                float a = 0.f;
                if (rr >= k && rr < s) {
                    a = (rr == k) ? (1.f + RIDGE)
                                  : sGram[((rr + 1) * SP1 + (k + 1)) * G + gq];
                    for (int m = 0; m < k; ++m)
                        a = fmaf(-sL[(rr * S1 + m) * G + gq],
                                 sL[(k * S1 + m) * G + gq], a);
                }
                float dk = __shfl(a, k);
                dk = fmaxf(dk, 0.5f * RIDGE);
                const float invd = 1.f / sqrtf(dk);
                if (rr >= k && rr < s) sL[(rr * S1 + k) * G + gq] = a * invd;
            }
            float trr = 0.f, acc = 0.f;
            const float rhs = (rr < s) ? sGram[((rr + 1) * SP1) * G + gq] : 0.f;
            for (int k = 0; k < s; ++k) {
                const float Lkk = sL[(k * S1 + k) * G + gq];
                float tk = (Lkk > 1e-20f) ? (rhs - acc) / Lkk : 0.f;
                tk = __shfl(tk, k);
                if (rr == k) trr = tk;
                if (rr > k && rr < s)
                    acc = fmaf(sL[(rr * S1 + k) * G + gq], tk, acc);
            }
            float crr = 0.f;
            acc = 0.f;
            for (int k = s - 1; k >= 0; --k) {
                const float Lkk = sL[(k * S1 + k) * G + gq];
                float ck = (Lkk > 1e-20f) ? (trr - acc) / Lkk : 0.f;
                ck = __shfl(ck, k);
                if (rr == k) crr = ck;
                if (rr < k) acc = fmaf(sL[(k * S1 + rr) * G + gq], ck, acc);
            }
            if (rr < s) {
                const float nu0 = sNu[gq];
                const float invn = sInv[(rr + 1) * G + gq];
                sD[rr * G + gq] = nu0 * crr * invn;
            }
        }
        __syncthreads();   // d visible

        // ---- update: w += sum d_i khat_i ----
        for (int i = 0; i < s; ++i)
            wsol = fmaf(sD[i * G + g], sK[(i * G + g) * VS + c], wsol);
        __syncthreads();   // reads done before next sweep overwrites
    }

    if (alive) out[sys * N + c] = 2.f * wsol - v_own;
}

extern "C" void kernel_launch(void* const* d_in, const int* in_sizes, int n_in,
                              void* d_out, int out_size, void* d_ws, size_t ws_size,
                              hipStream_t stream) {
    const float* x = (const float*)d_in[0];   // (B*T, 256)
    const float* P = (const float*)d_in[1];   // skew_param (256,256)
    const float* v = (const float*)d_in[2];   // (1,256)
    float* out = (float*)d_out;
    const int batch = in_sizes[0] / N;        // B*T

    const int nblk = (batch + G - 1) / G;     // 512 blocks -> 2 per CU
    hipLaunchKernelGGL(cayley_v10, dim3(nblk), dim3(BLK), 0, stream, x, P, v, out, batch);
}

// Round 11
// 103.480 us; speedup vs baseline: 1.8295x; 1.8295x over previous
//
#include <hip/hip_runtime.h>
#include <math.h>

#define N 256
#define G 4
#define BLK 1024
#define S1 12         // Krylov steps, sweep 1
#define S2 10         // Krylov steps, sweep 2
#define SP1 13        // S1+1
#define VS 268        // f32 K row stride (words), 16B-aligned (1072 B)
#define UTS 280       // f16 uT row stride (560 B = 35*16, keeps b128 alignment)
#define RIDGE 3e-5f

typedef _Float16 half8v __attribute__((ext_vector_type(8)));
typedef float float4v __attribute__((ext_vector_type(4)));

// ---- LDS arena (bytes), 16-aligned ----
#define OFF_K     0          // SP1*G*VS*4 = 55744 : K[(i*G+g)*VS + c]  (raw, sigma=1)
#define OFF_UT0   55744      // 4*UTS*2 = 2240 : f16 u staging, buffer 0
#define OFF_UT1   57984      // 2240 : buffer 1
#define OFF_ZTW   60224      // 16*64*4 = 4096 : MFMA out staging
#define OFF_GRAM  64320      // SP1*SP1*G*4 = 2704 : Gram[(i*SP1+j)*G+g]
#define OFF_INVN  67024      // SP1*G*4 = 208
#define OFF_L     67232      // S1*S1*G*4 = 2304 : chol L
#define OFF_D     69536      // S1*G*4 = 192 : update coeffs e_i
#define ARENA_SZ  69728

// B-fragment read: lane provides B[k=32t+8mq+j][n=mn]; systems live in rows 0..3,
// (mn&3) makes cols 4..15 duplicates (broadcast-friendly, no garbage rows needed).
#define LD_FRAG(base, t) (*(const half8v*)((base) + (mn & 3) * UTS + 32 * (t) + 8 * mq))

// zm = (S (x.*q))[c] for this thread's (c,g); q staged f16 at basep.
#define MATVEC(basep, dst) do {                                                        \
    float4v acc0 = {0.f, 0.f, 0.f, 0.f};                                               \
    float4v acc1 = {0.f, 0.f, 0.f, 0.f};                                               \
    _Pragma("unroll")                                                                  \
    for (int t = 0; t < 4; ++t) {                                                      \
        acc0 = __builtin_amdgcn_mfma_f32_16x16x32_f16(Shi[t], LD_FRAG(basep, t), acc0, 0, 0, 0);          \
        acc1 = __builtin_amdgcn_mfma_f32_16x16x32_f16(Shi[t + 4], LD_FRAG(basep, t + 4), acc1, 0, 0, 0);  \
    }                                                                                  \
    float4v accs = acc0 + acc1;                                                        \
    if (mn < 4) *(float4v*)(zTw + wv * 64 + mn * 16 + mq * 4) = accs;                  \
    dst = zTw[wv * 64 + g * 16 + coff];                                                \
} while (0)

// CA-GMRES + fp32 IR: unnormalized monomial basis (A k_i = k_{i+1} exactly),
// 1 barrier per basis step (double-buffered u staging, no per-step reductions);
// normalization deferred to the Gram diagonal.
__global__ __launch_bounds__(BLK, 4) void cayley_v11(const float* __restrict__ x_all,
                                                     const float* __restrict__ P,
                                                     const float* __restrict__ v_in,
                                                     float* __restrict__ out, int batch) {
    __shared__ __align__(16) char arena[ARENA_SZ];
    float* sK      = (float*)(arena + OFF_K);
    _Float16* uT0  = (_Float16*)(arena + OFF_UT0);
    _Float16* uT1  = (_Float16*)(arena + OFF_UT1);
    float* zTw     = (float*)(arena + OFF_ZTW);
    float* sGram   = (float*)(arena + OFF_GRAM);
    float* sInvN   = (float*)(arena + OFF_INVN);
    float* sL      = (float*)(arena + OFF_L);
    float* sD      = (float*)(arena + OFF_D);

    const int tid = threadIdx.x;
    const int lane = tid & 63, wv = tid >> 6;
    const int mn = lane & 15, mq = lane >> 4;        // MFMA fragment coords
    const int c = tid >> 2, g = tid & 3;             // solver coords
    const int coff = lane >> 2;                      // c & 15
    const int sys = blockIdx.x * G + g;
    const bool alive = sys < batch;

    // ---- preamble: S = P - P^T rows [16wv,16wv+16) as f16 A-fragments ----
    half8v Shi[8];
    {
        const int r = 16 * wv + mn;
#pragma unroll
        for (int t = 0; t < 8; ++t) {
            const int k0 = 32 * t + 8 * mq;
            float4v pa = *(const float4v*)(P + r * N + k0);
            float4v pb = *(const float4v*)(P + r * N + k0 + 4);
            half8v hi;
            hi[0] = (_Float16)(pa.x - P[(k0 + 0) * N + r]);
            hi[1] = (_Float16)(pa.y - P[(k0 + 1) * N + r]);
            hi[2] = (_Float16)(pa.z - P[(k0 + 2) * N + r]);
            hi[3] = (_Float16)(pa.w - P[(k0 + 3) * N + r]);
            hi[4] = (_Float16)(pb.x - P[(k0 + 4) * N + r]);
            hi[5] = (_Float16)(pb.y - P[(k0 + 5) * N + r]);
            hi[6] = (_Float16)(pb.z - P[(k0 + 6) * N + r]);
            hi[7] = (_Float16)(pb.w - P[(k0 + 7) * N + r]);
            Shi[t] = hi;
        }
    }

    const float x_own = alive ? x_all[sys * N + c] : 0.f;
    const float v_own = v_in[c];
    float wsol = 0.f;

    for (int sw = 0; sw < 2; ++sw) {
        const int s = sw ? S2 : S1;

        // ---- k_0 = fp32 residual through the f16 operator ----
        float kq;
        if (sw == 0) {
            kq = alive ? v_own : 0.f;
        } else {
            uT1[g * UTS + c] = (_Float16)(x_own * wsol);
            __syncthreads();
            float zm;
            MATVEC(uT1, zm);
            kq = alive ? (v_own - wsol - zm) : 0.f;
            // writing uT0 below is safe: concurrent laggards read uT1 only
        }
        sK[g * VS + c] = kq;
        uT0[g * UTS + c] = (_Float16)(x_own * kq);
        __syncthreads();                                   // B_0: buf0 + k_0 visible

        // ---- basis build: k_i = A k_{i-1}; 1 barrier/step ----
        for (int i = 1; i <= s; ++i) {
            float zm;
            if (i & 1) { MATVEC(uT0, zm); } else { MATVEC(uT1, zm); }
            kq += zm;                                      // A k = k + S(x.*k)
            sK[(i * G + g) * VS + c] = kq;
            if (i < s) {
                _Float16* dst = (i & 1) ? uT1 : uT0;       // write the other buffer
                dst[g * UTS + c] = (_Float16)(x_own * kq);
            }
            __syncthreads();
        }

        // ---- Gram pass: all pairs i<=j (incl. diagonal) over 16 waves ----
        const int NP = (s + 1) * (s + 2) / 2;
        for (int pp = wv; pp < NP; pp += 16) {
            int i = 0, rem = pp;
            while (rem >= (s + 1 - i)) { rem -= (s + 1 - i); ++i; }
            const int j = i + rem;
            const int gq = lane >> 4, q = lane & 15;
            const float* ka = sK + (i * G + gq) * VS + 16 * q;
            const float* kb = sK + (j * G + gq) * VS + 16 * q;
            float p;
            {
                float4v a0 = *(const float4v*)(ka);
                float4v b0 = *(const float4v*)(kb);
                float4v a1 = *(const float4v*)(ka + 4);
                float4v b1 = *(const float4v*)(kb + 4);
                p = a0.x * b0.x;
                p = fmaf(a0.y, b0.y, p); p = fmaf(a0.z, b0.z, p); p = fmaf(a0.w, b0.w, p);
                p = fmaf(a1.x, b1.x, p); p = fmaf(a1.y, b1.y, p);
                p = fmaf(a1.z, b1.z, p); p = fmaf(a1.w, b1.w, p);
            }
            {
                float4v a0 = *(const float4v*)(ka + 8);
                float4v b0 = *(const float4v*)(kb + 8);
                float4v a1 = *(const float4v*)(ka + 12);
                float4v b1 = *(const float4v*)(kb + 12);
                p = fmaf(a0.x, b0.x, p); p = fmaf(a0.y, b0.y, p);
                p = fmaf(a0.z, b0.z, p); p = fmaf(a0.w, b0.w, p);
                p = fmaf(a1.x, b1.x, p); p = fmaf(a1.y, b1.y, p);
                p = fmaf(a1.z, b1.z, p); p = fmaf(a1.w, b1.w, p);
            }
            p += __shfl_xor(p, 1); p += __shfl_xor(p, 2);
            p += __shfl_xor(p, 4); p += __shfl_xor(p, 8);
            if (q == 0) {
                sGram[(i * SP1 + j) * G + gq] = p;
                if (i != j) sGram[(j * SP1 + i) * G + gq] = p;
            }
        }
        __syncthreads();

        // ---- column norms from the Gram diagonal ----
        if (tid < 4 * (s + 1)) {
            const int i = tid >> 2, gq = tid & 3;
            const float dii = sGram[(i * SP1 + i) * G + gq];
            sInvN[i * G + gq] = (dii > 1e-30f) ? (1.f / sqrtf(dii)) : 0.f;
        }
        __syncthreads();

        // ---- per-system LSQ on normalized Gram: (Ghat[1:,1:]+ridge) chat = Ghat[1:,0];
        // wave-parallel Cholesky (wv<4 -> system wv; lanes = rows) ----
        if (wv < 4) {
            const int gq = wv;
            const int rr = lane;
            const float inv_r = (rr < s) ? sInvN[(rr + 1) * G + gq] : 0.f;
            for (int k = 0; k < s; ++k) {
                float a = 0.f;
                if (rr >= k && rr < s) {
                    a = (rr == k) ? (1.f + RIDGE)
                                  : sGram[((rr + 1) * SP1 + (k + 1)) * G + gq]
                                        * inv_r * sInvN[(k + 1) * G + gq];
                    for (int m = 0; m < k; ++m)
                        a = fmaf(-sL[(rr * S1 + m) * G + gq],
                                 sL[(k * S1 + m) * G + gq], a);
                }
                float dk = __shfl(a, k);
                dk = fmaxf(dk, 0.5f * RIDGE);
                const float invd = 1.f / sqrtf(dk);
                if (rr >= k && rr < s) sL[(rr * S1 + k) * G + gq] = a * invd;
            }
            // forward solve L t = rhs  (rhs_r = Ghat[r+1][0])
            float trr = 0.f, acc = 0.f;
            const float rhs = (rr < s)
                ? sGram[((rr + 1) * SP1) * G + gq] * inv_r * sInvN[gq] : 0.f;
            for (int k = 0; k < s; ++k) {
                const float Lkk = sL[(k * S1 + k) * G + gq];
                float tk = (Lkk > 1e-20f) ? (rhs - acc) / Lkk : 0.f;
                tk = __shfl(tk, k);
                if (rr == k) trr = tk;
                if (rr > k && rr < s)
                    acc = fmaf(sL[(rr * S1 + k) * G + gq], tk, acc);
            }
            // backward solve L^T chat = t
            float crr = 0.f;
            acc = 0.f;
            for (int k = s - 1; k >= 0; --k) {
                const float Lkk = sL[(k * S1 + k) * G + gq];
                float ck = (Lkk > 1e-20f) ? (trr - acc) / Lkk : 0.f;
                ck = __shfl(ck, k);
                if (rr == k) crr = ck;
                if (rr < k) acc = fmaf(sL[(k * S1 + rr) * G + gq], ck, acc);
            }
            // e_i = n0 * chat_i * invn_{i+1}  (coefficients on RAW k_i)
            if (rr < s) {
                const float n0 = sqrtf(fmaxf(sGram[0 * G + gq], 0.f));
                sD[rr * G + gq] = n0 * crr * sInvN[(rr + 1) * G + gq];
            }
        }
        __syncthreads();   // e visible

        // ---- update: w += sum e_i k_i (raw basis) ----
        for (int i = 0; i < s; ++i)
            wsol = fmaf(sD[i * G + g], sK[(i * G + g) * VS + c], wsol);
        __syncthreads();   // reads done before next sweep overwrites
    }

    if (alive) out[sys * N + c] = 2.f * wsol - v_own;
}

extern "C" void kernel_launch(void* const* d_in, const int* in_sizes, int n_in,
                              void* d_out, int out_size, void* d_ws, size_t ws_size,
                              hipStream_t stream) {
    const float* x = (const float*)d_in[0];   // (B*T, 256)
    const float* P = (const float*)d_in[1];   // skew_param (256,256)
    const float* v = (const float*)d_in[2];   // (1,256)
    float* out = (float*)d_out;
    const int batch = in_sizes[0] / N;        // B*T

    const int nblk = (batch + G - 1) / G;
    hipLaunchKernelGGL(cayley_v11, dim3(nblk), dim3(BLK), 0, stream, x, P, v, out, batch);
}

// Round 12
// 97.765 us; speedup vs baseline: 1.9364x; 1.0585x over previous
//
#include <hip/hip_runtime.h>
#include <math.h>

#define N 256
#define G 4
#define BLK 1024
#define S1 10         // Krylov steps, sweep 1
#define S2 8          // Krylov steps, sweep 2
#define SP1 11        // S1+1
#define VS 268        // f32 K row stride (words), 16B-aligned
#define UTS 280       // f16 uT row stride
#define RIDGE 3e-5f

typedef _Float16 half8v __attribute__((ext_vector_type(8)));
typedef float float4v __attribute__((ext_vector_type(4)));

// ---- LDS arena (bytes), 16-aligned ----
#define OFF_K     0          // SP1*G*VS*4 = 47168 : K[(i*G+g)*VS + c]  (raw shifted basis)
#define OFF_UT0   47168      // 4*UTS*2 = 2240 : f16 u staging, buffer 0
#define OFF_UT1   49408      // 2240 : buffer 1
#define OFF_ZTW   51648      // 16*64*4 = 4096 : MFMA out staging
#define OFF_GRAM  55744      // SP1*SP1*G*4 = 1936 : Gram[(i*SP1+j)*G+g]
#define OFF_L     57680      // S1*S1*G*4 = 1600 : chol L
#define OFF_D     59280      // S1*G*4 = 160 : update coeffs c_i
#define ARENA_SZ  59456

// B-fragment read: lane provides B[k=32t+8mq+j][n=mn]; systems in rows 0..3,
// (mn&3) duplicates them into cols 4..15 (broadcast-friendly).
#define LD_FRAG(base, t) (*(const half8v*)((base) + (mn & 3) * UTS + 32 * (t) + 8 * mq))

// zm = (S (x.*q))[c] for this thread's (c,g); q staged f16 at basep.
#define MATVEC(basep, dst) do {                                                        \
    float4v acc0 = {0.f, 0.f, 0.f, 0.f};                                               \
    float4v acc1 = {0.f, 0.f, 0.f, 0.f};                                               \
    _Pragma("unroll")                                                                  \
    for (int t = 0; t < 4; ++t) {                                                      \
        acc0 = __builtin_amdgcn_mfma_f32_16x16x32_f16(Shi[t], LD_FRAG(basep, t), acc0, 0, 0, 0);          \
        acc1 = __builtin_amdgcn_mfma_f32_16x16x32_f16(Shi[t + 4], LD_FRAG(basep, t + 4), acc1, 0, 0, 0);  \
    }                                                                                  \
    float4v accs = acc0 + acc1;                                                        \
    if (mn < 4) *(float4v*)(zTw + wv * 64 + mn * 16 + mq * 4) = accs;                  \
    dst = zTw[wv * 64 + g * 16 + coff];                                                \
} while (0)

// CA-GMRES + fp32 IR with SHIFTED Newton basis: k_{i+1} = 0.5*Sx*k_i (spectral
// center of A = I + Sx removed -> far better Gram conditioning than A-powers).
// Arnoldi-free identity: A k_i = k_i + 2 k_{i+1}. LSQ matrix = (1,2,2,4)-stencil
// of the Gram matrix; per-system ridge-Cholesky; fp32 residual between sweeps.
__global__ __launch_bounds__(BLK, 4) void cayley_v12(const float* __restrict__ x_all,
                                                     const float* __restrict__ P,
                                                     const float* __restrict__ v_in,
                                                     float* __restrict__ out, int batch) {
    __shared__ __align__(16) char arena[ARENA_SZ];
    float* sK      = (float*)(arena + OFF_K);
    _Float16* uT0  = (_Float16*)(arena + OFF_UT0);
    _Float16* uT1  = (_Float16*)(arena + OFF_UT1);
    float* zTw     = (float*)(arena + OFF_ZTW);
    float* sGram   = (float*)(arena + OFF_GRAM);
    float* sL      = (float*)(arena + OFF_L);
    float* sD      = (float*)(arena + OFF_D);

    const int tid = threadIdx.x;
    const int lane = tid & 63, wv = tid >> 6;
    const int mn = lane & 15, mq = lane >> 4;        // MFMA fragment coords
    const int c = tid >> 2, g = tid & 3;             // solver coords
    const int coff = lane >> 2;                      // c & 15
    const int sys = blockIdx.x * G + g;
    const bool alive = sys < batch;

    // ---- preamble: S = P - P^T rows [16wv,16wv+16) as f16 A-fragments ----
    half8v Shi[8];
    {
        const int r = 16 * wv + mn;
#pragma unroll
        for (int t = 0; t < 8; ++t) {
            const int k0 = 32 * t + 8 * mq;
            float4v pa = *(const float4v*)(P + r * N + k0);
            float4v pb = *(const float4v*)(P + r * N + k0 + 4);
            half8v hi;
            hi[0] = (_Float16)(pa.x - P[(k0 + 0) * N + r]);
            hi[1] = (_Float16)(pa.y - P[(k0 + 1) * N + r]);
            hi[2] = (_Float16)(pa.z - P[(k0 + 2) * N + r]);
            hi[3] = (_Float16)(pa.w - P[(k0 + 3) * N + r]);
            hi[4] = (_Float16)(pb.x - P[(k0 + 4) * N + r]);
            hi[5] = (_Float16)(pb.y - P[(k0 + 5) * N + r]);
            hi[6] = (_Float16)(pb.z - P[(k0 + 6) * N + r]);
            hi[7] = (_Float16)(pb.w - P[(k0 + 7) * N + r]);
            Shi[t] = hi;
        }
    }

    const float x_own = alive ? x_all[sys * N + c] : 0.f;
    const float v_own = v_in[c];
    float wsol = 0.f;

    for (int sw = 0; sw < 2; ++sw) {
        const int s = sw ? S2 : S1;

        // ---- k_0 = fp32 residual through the f16 operator ----
        float kq;
        if (sw == 0) {
            kq = alive ? v_own : 0.f;
        } else {
            uT1[g * UTS + c] = (_Float16)(x_own * wsol);
            __syncthreads();
            float zm;
            MATVEC(uT1, zm);
            kq = alive ? (v_own - wsol - zm) : 0.f;
            // writing uT0 below is safe: laggards read uT1/zTw-own-slot only
        }
        sK[g * VS + c] = kq;
        uT0[g * UTS + c] = (_Float16)(x_own * kq);
        __syncthreads();                                   // buf0 + k_0 visible

        // ---- basis build: k_{i} = 0.5 * Sx k_{i-1}; 1 barrier/step ----
        for (int i = 1; i <= s; ++i) {
            float zm;
            if (i & 1) { MATVEC(uT0, zm); } else { MATVEC(uT1, zm); }
            kq = 0.5f * zm;                                // shifted+scaled basis
            sK[(i * G + g) * VS + c] = kq;
            if (i < s) {
                _Float16* dst = (i & 1) ? uT1 : uT0;
                dst[g * UTS + c] = (_Float16)(x_own * kq);
            }
            __syncthreads();
        }

        // ---- Gram pass: all pairs i<=j (incl. diagonal) over 16 waves ----
        const int NP = (s + 1) * (s + 2) / 2;
        for (int pp = wv; pp < NP; pp += 16) {
            int i = 0, rem = pp;
            while (rem >= (s + 1 - i)) { rem -= (s + 1 - i); ++i; }
            const int j = i + rem;
            const int gq = lane >> 4, q = lane & 15;
            const float* ka = sK + (i * G + gq) * VS + 16 * q;
            const float* kb = sK + (j * G + gq) * VS + 16 * q;
            float p;
            {
                float4v a0 = *(const float4v*)(ka);
                float4v b0 = *(const float4v*)(kb);
                float4v a1 = *(const float4v*)(ka + 4);
                float4v b1 = *(const float4v*)(kb + 4);
                p = a0.x * b0.x;
                p = fmaf(a0.y, b0.y, p); p = fmaf(a0.z, b0.z, p); p = fmaf(a0.w, b0.w, p);
                p = fmaf(a1.x, b1.x, p); p = fmaf(a1.y, b1.y, p);
                p = fmaf(a1.z, b1.z, p); p = fmaf(a1.w, b1.w, p);
            }
            {
                float4v a0 = *(const float4v*)(ka + 8);
                float4v b0 = *(const float4v*)(kb + 8);
                float4v a1 = *(const float4v*)(ka + 12);
                float4v b1 = *(const float4v*)(kb + 12);
                p = fmaf(a0.x, b0.x, p); p = fmaf(a0.y, b0.y, p);
                p = fmaf(a0.z, b0.z, p); p = fmaf(a0.w, b0.w, p);
                p = fmaf(a1.x, b1.x, p); p = fmaf(a1.y, b1.y, p);
                p = fmaf(a1.z, b1.z, p); p = fmaf(a1.w, b1.w, p);
            }
            p += __shfl_xor(p, 1); p += __shfl_xor(p, 2);
            p += __shfl_xor(p, 4); p += __shfl_xor(p, 8);
            if (q == 0) {
                sGram[(i * SP1 + j) * G + gq] = p;
                if (i != j) sGram[(j * SP1 + i) * G + gq] = p;
            }
        }
        __syncthreads();

        // ---- per-system LSQ: B = (1,2,2,4)-stencil of Gram; solve
        // (Bhat + ridge) chat = rhs_hat via wave-parallel Cholesky ----
        if (wv < 4) {
            const int gq = wv;
            const int rr = lane;
#define GG(i, j) sGram[((i) * SP1 + (j)) * G + gq]
            float invn_r = 0.f;
            if (rr < s) {
                const float Brr = GG(rr, rr) + 4.f * GG(rr, rr + 1)
                                + 4.f * GG(rr + 1, rr + 1);
                invn_r = (Brr > 1e-30f) ? (1.f / sqrtf(Brr)) : 0.f;
            }
            for (int k = 0; k < s; ++k) {
                const float invn_k = __shfl(invn_r, k);
                float a = 0.f;
                if (rr >= k && rr < s) {
                    if (rr == k) {
                        a = 1.f + RIDGE;
                    } else {
                        const float Brk = GG(rr, k) + 2.f * GG(rr, k + 1)
                                        + 2.f * GG(rr + 1, k) + 4.f * GG(rr + 1, k + 1);
                        a = Brk * invn_r * invn_k;
                    }
                    for (int m = 0; m < k; ++m)
                        a = fmaf(-sL[(rr * S1 + m) * G + gq],
                                 sL[(k * S1 + m) * G + gq], a);
                }
                float dk = __shfl(a, k);
                dk = fmaxf(dk, 0.5f * RIDGE);
                const float invd = 1.f / sqrtf(dk);
                if (rr >= k && rr < s) sL[(rr * S1 + k) * G + gq] = a * invd;
            }
            // forward solve L t = rhs_hat
            float trr = 0.f, acc = 0.f;
            const float rhs = (rr < s)
                ? (GG(rr, 0) + 2.f * GG(rr + 1, 0)) * invn_r : 0.f;
#undef GG
            for (int k = 0; k < s; ++k) {
                const float Lkk = sL[(k * S1 + k) * G + gq];
                float tk = (Lkk > 1e-20f) ? (rhs - acc) / Lkk : 0.f;
                tk = __shfl(tk, k);
                if (rr == k) trr = tk;
                if (rr > k && rr < s)
                    acc = fmaf(sL[(rr * S1 + k) * G + gq], tk, acc);
            }
            // backward solve L^T chat = t
            float crr = 0.f;
            acc = 0.f;
            for (int k = s - 1; k >= 0; --k) {
                const float Lkk = sL[(k * S1 + k) * G + gq];
                float ck = (Lkk > 1e-20f) ? (trr - acc) / Lkk : 0.f;
                ck = __shfl(ck, k);
                if (rr == k) crr = ck;
                if (rr < k) acc = fmaf(sL[(k * S1 + rr) * G + gq], ck, acc);
            }
            if (rr < s) sD[rr * G + gq] = crr * invn_r;   // c_i on raw k_i
        }
        __syncthreads();   // c visible

        // ---- update: w += sum c_i k_i ----
        for (int i = 0; i < s; ++i)
            wsol = fmaf(sD[i * G + g], sK[(i * G + g) * VS + c], wsol);
        __syncthreads();   // reads done before next sweep overwrites
    }

    if (alive) out[sys * N + c] = 2.f * wsol - v_own;
}

extern "C" void kernel_launch(void* const* d_in, const int* in_sizes, int n_in,
                              void* d_out, int out_size, void* d_ws, size_t ws_size,
                              hipStream_t stream) {
    const float* x = (const float*)d_in[0];   // (B*T, 256)
    const float* P = (const float*)d_in[1];   // skew_param (256,256)
    const float* v = (const float*)d_in[2];   // (1,256)
    float* out = (float*)d_out;
    const int batch = in_sizes[0] / N;        // B*T

    const int nblk = (batch + G - 1) / G;
    hipLaunchKernelGGL(cayley_v12, dim3(nblk), dim3(BLK), 0, stream, x, P, v, out, batch);
}